// Round 2
// baseline (504.200 us; speedup 1.0000x reference)
//
#include <hip/hip_runtime.h>
#include <math.h>

// Problem constants (from reference):
//   x: (16, 256, 128, 128) fp32 ; w: (8, 32, 32) fp32 ; logdet: (16,) fp32
//   z[b, k*32+d, h, w] = sum_c W[k][d][c] * x[b, k*32+c, h, w]
//   out = [z flat (67108864 floats)] ++ [logdet + sum_k log|det W_k| * 16384  (16 floats)]
#define HW    16384   // 128*128
#define NB    8
#define BC    32
#define BATCH 16
#define Z_ELEMS (16 * 256 * HW)   // 67108864

// Native Clang vector type: required by __builtin_nontemporal_load/store
// (HIP's float4 is a class and is rejected).
typedef float v4f __attribute__((ext_vector_type(4)));

// ---------------------------------------------------------------------------
// Main streaming kernel: block-diagonal 1x1 conv.
// grid = 2048 blocks, 256 threads. Each block: 1024 pixels of one (b,k) slice.
// Each thread: one float4 (4 pixel columns), acc[32] in VGPRs, c-loop with
// 2-deep manual prefetch. Weights are wave-uniform -> scalar loads (s_load).
// ---------------------------------------------------------------------------
__global__ __launch_bounds__(256) void conv_kernel(const float* __restrict__ x,
                                                   const float* __restrict__ w,
                                                   float* __restrict__ out) {
    const int tid = threadIdx.x;
    const int blk = blockIdx.x;
    const int s   = blk >> 4;              // slice id in [0,128): s = b*8 + k
    const int k   = s & 7;                 // weight block
    const int pix = ((blk & 15) << 10) + (tid << 2);

    const size_t base = (size_t)s * (BC * HW);
    const float* xp = x   + base + pix;
    float*       op = out + base + pix;
    const float* wk = w + k * (BC * BC);   // wave-uniform pointer

    v4f acc[BC];
#pragma unroll
    for (int d = 0; d < BC; ++d) acc[d] = (v4f)(0.f);

    // prime the 2-deep pipeline
    v4f cur0 = __builtin_nontemporal_load((const v4f*)(xp));
    v4f cur1 = __builtin_nontemporal_load((const v4f*)(xp + HW));

    for (int c = 0; c < BC; c += 2) {
        v4f nxt0 = (v4f)(0.f), nxt1 = (v4f)(0.f);
        if (c + 2 < BC) {
            nxt0 = __builtin_nontemporal_load((const v4f*)(xp + (size_t)(c + 2) * HW));
            nxt1 = __builtin_nontemporal_load((const v4f*)(xp + (size_t)(c + 3) * HW));
        }
#pragma unroll
        for (int d = 0; d < BC; ++d) {
            const float w0 = wk[d * BC + c];       // uniform -> SGPR
            const float w1 = wk[d * BC + c + 1];   // uniform -> SGPR
            acc[d] += w0 * cur0;
            acc[d] += w1 * cur1;
        }
        cur0 = nxt0;
        cur1 = nxt1;
    }

#pragma unroll
    for (int d = 0; d < BC; ++d) {
        __builtin_nontemporal_store(acc[d], (v4f*)(op + (size_t)d * HW));
    }
}

// ---------------------------------------------------------------------------
// Logdet kernel: 1 block, 512 threads = 8 waves; wave k LU-factorizes W_k
// (partial pivoting) in LDS, accumulates log|pivot|; then threads 0..15
// write the 16 logdet outputs.
// ---------------------------------------------------------------------------
__global__ __launch_bounds__(512) void logdet_kernel(const float* __restrict__ w,
                                                     const float* __restrict__ ld_in,
                                                     float* __restrict__ out) {
    __shared__ float m[NB][BC][BC + 1];   // +1 pad: no bank conflicts
    __shared__ float ldpart[NB];

    const int tid  = threadIdx.x;
    const int wv   = tid >> 6;    // wave id == matrix id
    const int lane = tid & 63;

    for (int idx = lane; idx < BC * BC; idx += 64)
        m[wv][idx >> 5][idx & 31] = w[wv * BC * BC + idx];
    __syncthreads();

    float ldsum = 0.f;
    for (int kk = 0; kk < BC; ++kk) {
        // serial pivot search on lane 0 (32 elements, cheap), broadcast
        int p = kk;
        if (lane == 0) {
            float best = fabsf(m[wv][kk][kk]);
            for (int i = kk + 1; i < BC; ++i) {
                float v = fabsf(m[wv][i][kk]);
                if (v > best) { best = v; p = i; }
            }
        }
        p = __shfl(p, 0);

        // swap rows kk <-> p (lanes 0..31 each move one column element)
        if (p != kk && lane < BC) {
            float t         = m[wv][kk][lane];
            m[wv][kk][lane] = m[wv][p][lane];
            m[wv][p][lane]  = t;
        }
        __syncthreads();

        const float pivot = m[wv][kk][kk];
        ldsum += logf(fabsf(pivot));

        // elimination: lane i (kk < i < 32) owns row i
        if (lane > kk && lane < BC) {
            const float f = m[wv][lane][kk] / pivot;
            for (int j = kk + 1; j < BC; ++j)
                m[wv][lane][j] -= f * m[wv][kk][j];
        }
        __syncthreads();
    }

    if (lane == 0) ldpart[wv] = ldsum;
    __syncthreads();

    if (tid < BATCH) {
        float tot = 0.f;
#pragma unroll
        for (int i = 0; i < NB; ++i) tot += ldpart[i];
        out[Z_ELEMS + tid] = ld_in[tid] + tot * (float)HW;
    }
}

extern "C" void kernel_launch(void* const* d_in, const int* in_sizes, int n_in,
                              void* d_out, int out_size, void* d_ws, size_t ws_size,
                              hipStream_t stream) {
    const float* x  = (const float*)d_in[0];
    const float* w  = (const float*)d_in[1];
    const float* ld = (const float*)d_in[2];
    float* out = (float*)d_out;

    conv_kernel<<<dim3(2048), dim3(256), 0, stream>>>(x, w, out);
    logdet_kernel<<<dim3(1), dim3(512), 0, stream>>>(w, ld, out);
}